// Round 11
// baseline (270.357 us; speedup 1.0000x reference)
//
#include <hip/hip_runtime.h>
#include <hip/hip_bf16.h>
#include <math.h>

#define Bq 64
#define Tq 2048
#define Eq 256
#define Dq 256
#define Iq 256

using short8  = __attribute__((ext_vector_type(8))) short;
using floatx4 = __attribute__((ext_vector_type(4))) float;

// tanh via fast exp + v_rcp approx (error ~1e-6, bf16 GEMM noise dominates)
__device__ __forceinline__ float fast_tanh(float x) {
    float e = __expf(2.0f * x);
    return fmaf(-2.0f, __builtin_amdgcn_rcpf(e + 1.0f), 1.0f);
}

__device__ __forceinline__ ushort f2bf(float x) {
    union { __hip_bfloat16 h; ushort u; } c;
    c.h = __float2bfloat16(x);
    return c.u;
}

// Fused prep:
//  blocks 0..31 : w1 fp32 -> bf16 fragment-ordered: w1sw[kc][i][8], kc=k/8
//  blocks 32..95: dec_proj[b][i] = sum_d dec[b][d]*w2[i][d], b=blockIdx-32
__global__ __launch_bounds__(256) void prep_kernel(
    const float* __restrict__ w1, ushort* __restrict__ w1sw,
    const float* __restrict__ dec, const float* __restrict__ w2,
    float* __restrict__ dproj)
{
    if (blockIdx.x < 32) {
        const int kc = blockIdx.x;
        const int i  = threadIdx.x;
        const float* src = w1 + i * Eq + kc * 8;
        float4 f0 = *(const float4*)src;
        float4 f1 = *(const float4*)(src + 4);
        ushort u[8] = { f2bf(f0.x), f2bf(f0.y), f2bf(f0.z), f2bf(f0.w),
                        f2bf(f1.x), f2bf(f1.y), f2bf(f1.z), f2bf(f1.w) };
        *(short8*)&w1sw[(kc * 256 + i) * 8] = *(short8*)u;
    } else {
        const int b = blockIdx.x - 32;
        const int i = threadIdx.x;
        __shared__ float dls[Dq];
        dls[i] = dec[b * Dq + i];
        __syncthreads();
        const float* w2r = w2 + i * Dq;
        float acc = 0.f;
        #pragma unroll 8
        for (int d = 0; d < Dq; d += 4) {
            float4 wv = *(const float4*)&w2r[d];
            float4 dv = *(const float4*)&dls[d];
            acc += wv.x * dv.x + wv.y * dv.y + wv.z * dv.z + wv.w * dv.w;
        }
        dproj[b * Iq + i] = acc;
    }
}

// per-tile epilogue: tanh + v-weight + score reduce + exp + ctx partial.
// RAW barriers only (lgkmcnt) so cross-tile prefetch loads stay in flight.
__device__ __forceinline__ void tile_epilogue(
    floatx4 (&acc)[4][4], const float (&vv)[4], const float (&dd)[4],
    float* swred, float* redf, const float* eb,
    float* __restrict__ escore, float* __restrict__ ctxp,
    float* __restrict__ denomp,
    int b, int bxx, int w, int l, int l15, int lq)
{
    float part[4][4];
    #pragma unroll
    for (int mi = 0; mi < 4; ++mi)
        #pragma unroll
        for (int r = 0; r < 4; ++r) part[mi][r] = 0.f;

    #pragma unroll
    for (int ni = 0; ni < 4; ++ni) {
        const float vi = vv[ni];
        const float dp = dd[ni];
        #pragma unroll
        for (int mi = 0; mi < 4; ++mi)
            #pragma unroll
            for (int r = 0; r < 4; ++r)
                part[mi][r] += vi * fast_tanh(acc[mi][ni][r] + dp);
    }

    #pragma unroll
    for (int mi = 0; mi < 4; ++mi)
        #pragma unroll
        for (int r = 0; r < 4; ++r) {
            float x = part[mi][r];
            x += __shfl_xor(x, 1); x += __shfl_xor(x, 2);
            x += __shfl_xor(x, 4); x += __shfl_xor(x, 8);
            part[mi][r] = x;
        }
    if (l15 == 0) {
        #pragma unroll
        for (int mi = 0; mi < 4; ++mi)
            #pragma unroll
            for (int r = 0; r < 4; ++r)
                swred[w * 64 + mi * 16 + lq * 4 + r] = part[mi][r];
    }
    asm volatile("s_waitcnt lgkmcnt(0)" ::: "memory");
    __builtin_amdgcn_s_barrier();
    __builtin_amdgcn_sched_barrier(0);

    // every wave redundantly computes all 64 exps (lane l -> t-local l).
    float s = swred[l] + swred[64 + l] + swred[128 + l] + swred[192 + l];
    const float es = __expf(s);     // |s| <= ~16 -> fp32-safe
    if (w == 0) {
        escore[(size_t)b * Tq + bxx * 64 + l] = es;
        float tot = es;
        tot += __shfl_xor(tot, 1);  tot += __shfl_xor(tot, 2);
        tot += __shfl_xor(tot, 4);  tot += __shfl_xor(tot, 8);
        tot += __shfl_xor(tot, 16); tot += __shfl_xor(tot, 32);
        if (l == 0) denomp[bxx * Bq + b] = tot;
    }

    // ctx partial: L2-hot fp32 re-read of this tile's enc rows.
    const int el = l * 4;
    float4 a = {0.f, 0.f, 0.f, 0.f};
    #pragma unroll 8
    for (int tt = 0; tt < 16; ++tt) {
        const int t = w * 16 + tt;
        const float pt = __shfl(es, t);
        float4 ev = *(const float4*)&eb[t * Eq + el];
        a.x += pt * ev.x; a.y += pt * ev.y; a.z += pt * ev.z; a.w += pt * ev.w;
    }
    *(float4*)&redf[w * 256 + el] = a;
    asm volatile("s_waitcnt lgkmcnt(0)" ::: "memory");
    __builtin_amdgcn_s_barrier();
    __builtin_amdgcn_sched_barrier(0);
    if (w == 0) {
        float4 a0 = *(const float4*)&redf[0 * 256 + el];
        float4 a1 = *(const float4*)&redf[1 * 256 + el];
        float4 a2 = *(const float4*)&redf[2 * 256 + el];
        float4 a3 = *(const float4*)&redf[3 * 256 + el];
        float4 o;
        o.x = a0.x + a1.x + a2.x + a3.x;
        o.y = a0.y + a1.y + a2.y + a3.y;
        o.z = a0.z + a1.z + a2.z + a3.z;
        o.w = a0.w + a1.w + a2.w + a3.w;
        *(float4*)&ctxp[((size_t)bxx * Bq + b) * Eq + el] = o;
    }
    // protect swred/redf (and As) before the next tile reuses them
    asm volatile("s_waitcnt lgkmcnt(0)" ::: "memory");
    __builtin_amdgcn_s_barrier();
    __builtin_amdgcn_sched_barrier(0);
}

// Fused scores + unnormalized-context, v9: R10 (depth-2 reg prefetch,
// non-draining barriers; 218.3us total) + PAIRED TILES:
//  Each block owns 2 consecutive t-tiles. Tile0's KSTEP(2)/(3) -- the dead
//  HBM-issue windows that capped R10 at ~2.5TB/s (40% duty) -- now issue
//  tile1's chunk0/1 loads; the epilogue (VALU/LDS/L2 only, raw barriers,
//  NO vmcnt drain) runs with those loads in flight, so tile1 starts with
//  data arrived and its prologue is just a CVTW. One full prologue per
//  2 tiles. Grid 1024 (16x64), 3 blocks/CU resident.
__global__ __launch_bounds__(256, 3) void scores_ctx_kernel(
    const float*  __restrict__ enc,    // [B][T][E] fp32
    const ushort* __restrict__ w1sw,   // fragment-ordered bf16 [32 kc][256 i][8]
    const float*  __restrict__ v,      // [I]
    const float*  __restrict__ dproj,  // [B][I]
    float* __restrict__ escore,        // [B][T] unnormalized exp (probs buffer)
    float* __restrict__ ctxp,          // [32][B][E] context partials
    float* __restrict__ denomp)        // [32][B]
{
    const int b   = blockIdx.y;
    const int bx0 = blockIdx.x * 2;    // first of this block's 2 tiles
    const int tid = threadIdx.x;
    const int w   = tid >> 6;
    const int l   = tid & 63;
    const int l15 = l & 15;
    const int lq  = l >> 4;

    __shared__ alignas(16) ushort As[2][64 * 72];  // 18.4 KB bf16 dbuf, pad 72
    __shared__ float swred[4 * 64];                // 1 KB
    __shared__ float redf[4 * 256];                // 4 KB

    float vv[4], dd[4];
    #pragma unroll
    for (int ni = 0; ni < 4; ++ni) {
        const int i = w * 64 + ni * 16 + l15;
        vv[ni] = v[i];
        dd[ni] = dproj[b * Iq + i];
    }

    floatx4 acc[4][4];

    const float* encT0 = enc + ((size_t)b * Tq + bx0 * 64) * Eq;
    const float* encT1 = encT0 + (size_t)64 * Eq;
    const int srow = tid >> 4;
    const int sc4  = (tid & 15) * 4;

    #define LOADC(eb, kt, st)                                                 \
        _Pragma("unroll")                                                     \
        for (int r = 0; r < 4; ++r)                                           \
            st[r] = *(const float4*)&eb[(srow + 16 * r) * Eq + (kt) * 64 + sc4];
    #define CVTW(st, buf)                                                     \
        _Pragma("unroll")                                                     \
        for (int r = 0; r < 4; ++r) {                                         \
            ushort4 u;                                                        \
            u.x = f2bf(st[r].x); u.y = f2bf(st[r].y);                         \
            u.z = f2bf(st[r].z); u.w = f2bf(st[r].w);                         \
            *(ushort4*)&As[buf][(srow + 16 * r) * 72 + sc4] = u;              \
        }
    #define BARRIER()                                                         \
        asm volatile("s_waitcnt lgkmcnt(0)" ::: "memory");                    \
        __builtin_amdgcn_s_barrier();                                         \
        __builtin_amdgcn_sched_barrier(0);

    const ushort* vb = w1sw + (w * 64 + l15) * 8 + lq * 2048;

    #define KSTEP(k, cur, LOADNEXT, CVTPREV)                                  \
    {                                                                         \
        short8 bfv[2][4];                                                     \
        _Pragma("unroll")                                                     \
        for (int ks = 0; ks < 2; ++ks)                                        \
            _Pragma("unroll")                                                 \
            for (int ni = 0; ni < 4; ++ni)                                    \
                bfv[ks][ni] = *(const short8*)(vb + ((k) * 8 + ks * 4) * 2048 \
                                               + ni * 128);                   \
        LOADNEXT                                                              \
        _Pragma("unroll")                                                     \
        for (int ks = 0; ks < 2; ++ks) {                                      \
            const int kloc = ks * 32 + lq * 8;                                \
            short8 af[4];                                                     \
            _Pragma("unroll")                                                 \
            for (int mi = 0; mi < 4; ++mi)                                    \
                af[mi] = *(const short8*)&As[cur][(mi * 16 + l15) * 72 + kloc];\
            __builtin_amdgcn_s_setprio(1);                                    \
            _Pragma("unroll")                                                 \
            for (int mi = 0; mi < 4; ++mi)                                    \
                _Pragma("unroll")                                             \
                for (int ni = 0; ni < 4; ++ni)                                \
                    acc[mi][ni] = __builtin_amdgcn_mfma_f32_16x16x32_bf16(    \
                        af[mi], bfv[ks][ni], acc[mi][ni], 0, 0, 0);           \
            __builtin_amdgcn_s_setprio(0);                                    \
        }                                                                     \
        CVTPREV                                                               \
    }

    float4 s0[4], s1[4];

    // ---------------- tile 0 ----------------
    LOADC(encT0, 0, s0);
    LOADC(encT0, 1, s1);
    CVTW(s0, 0);
    BARRIER();

    #pragma unroll
    for (int mi = 0; mi < 4; ++mi)
        #pragma unroll
        for (int ni = 0; ni < 4; ++ni)
            acc[mi][ni] = (floatx4)0.f;

    KSTEP(0, 0, LOADC(encT0, 2, s0);, CVTW(s1, 1); BARRIER();)
    KSTEP(1, 1, LOADC(encT0, 3, s1);, CVTW(s0, 0); BARRIER();)
    KSTEP(2, 0, LOADC(encT1, 0, s0);, CVTW(s1, 1); BARRIER();)  // cross-tile
    KSTEP(3, 1, LOADC(encT1, 1, s1);, ;)                        // prefetch

    tile_epilogue(acc, vv, dd, swred, redf, encT0,
                  escore, ctxp, denomp, b, bx0, w, l, l15, lq);

    // ---------------- tile 1 ----------------
    CVTW(s0, 0);        // chunk0 loads issued back in tile0 KSTEP(2)
    BARRIER();

    #pragma unroll
    for (int mi = 0; mi < 4; ++mi)
        #pragma unroll
        for (int ni = 0; ni < 4; ++ni)
            acc[mi][ni] = (floatx4)0.f;

    KSTEP(0, 0, LOADC(encT1, 2, s0);, CVTW(s1, 1); BARRIER();)
    KSTEP(1, 1, LOADC(encT1, 3, s1);, CVTW(s0, 0); BARRIER();)
    KSTEP(2, 0, ;,                    CVTW(s1, 1); BARRIER();)
    KSTEP(3, 1, ;,                    ;)

    tile_epilogue(acc, vv, dd, swred, redf, encT1,
                  escore, ctxp, denomp, b, bx0 + 1, w, l, l15, lq);

    #undef KSTEP
    #undef LOADC
    #undef CVTW
    #undef BARRIER
}

// One block per b: denom = sum_c denomp[c][b]; probs *= 1/denom (in place);
// ctx[b][e] = (sum_c ctxp[c][b][e]) / denom.
__global__ __launch_bounds__(256) void finalize_kernel(
    const float* __restrict__ ctxp, const float* __restrict__ denomp,
    float* __restrict__ probs, float* __restrict__ ctx)
{
    const int b   = blockIdx.x;
    const int tid = threadIdx.x;

    float d = denomp[(tid & 31) * Bq + b];
    d += __shfl_xor(d, 1);  d += __shfl_xor(d, 2);  d += __shfl_xor(d, 4);
    d += __shfl_xor(d, 8);  d += __shfl_xor(d, 16);
    const float inv = 1.0f / d;

    float* prow = probs + (size_t)b * Tq + tid * 8;
    float4 p0 = *(const float4*)(prow + 0);
    float4 p1 = *(const float4*)(prow + 4);
    p0.x *= inv; p0.y *= inv; p0.z *= inv; p0.w *= inv;
    p1.x *= inv; p1.y *= inv; p1.z *= inv; p1.w *= inv;
    *(float4*)(prow + 0) = p0;
    *(float4*)(prow + 4) = p1;

    float s = 0.f;
    #pragma unroll 8
    for (int c = 0; c < 32; ++c)
        s += ctxp[((size_t)c * Bq + b) * Eq + tid];
    ctx[b * Eq + tid] = s * inv;
}

extern "C" void kernel_launch(void* const* d_in, const int* in_sizes, int n_in,
                              void* d_out, int out_size, void* d_ws, size_t ws_size,
                              hipStream_t stream) {
    const float* enc = (const float*)d_in[0];  // [64][2048][256]
    const float* dec = (const float*)d_in[1];  // [64][256]
    const float* w1  = (const float*)d_in[2];  // [256][256]
    const float* w2  = (const float*)d_in[3];  // [256][256]
    const float* v   = (const float*)d_in[4];  // [1][256]

    float* out   = (float*)d_out;
    float* ctx   = out;                 // [64][256]  output 0
    float* probs = out + Bq * Eq;       // [64][2048] output 1 (escore first)

    char* ws = (char*)d_ws;
    float*  ctxp   = (float*)ws;                        // 2 MB  [32][64][256]
    float*  denomp = (float*)(ws + (32*Bq*Eq)*4);       // 8 KB  [32][64]
    float*  dproj  = (float*)(ws + (32*Bq*Eq)*4 + 32*Bq*4);          // 64 KB
    ushort* w1sw   = (ushort*)(ws + (32*Bq*Eq)*4 + 32*Bq*4 + Bq*Iq*4); // 128 KB

    // all ws buffers are fully overwritten each call -> no memsets needed
    prep_kernel<<<dim3(96), dim3(256), 0, stream>>>(w1, w1sw, dec, w2, dproj);
    scores_ctx_kernel<<<dim3(Tq / 128, Bq), dim3(256), 0, stream>>>(
        enc, w1sw, v, dproj, probs, ctxp, denomp);
    finalize_kernel<<<dim3(Bq), dim3(256), 0, stream>>>(ctxp, denomp, probs, ctx);
}